// Round 8
// baseline (881.710 us; speedup 1.0000x reference)
//
#include <hip/hip_runtime.h>
#include <hip/hip_bf16.h>

#define LL 4
#define GG 8
#define HH 2048
#define RR 128
#define SS 512
#define AOUT 64
#define BBB 4096

typedef __bf16 bf16x8 __attribute__((ext_vector_type(8)));
typedef float f32x4 __attribute__((ext_vector_type(4)));

__device__ __forceinline__ unsigned short f2b(float v) {
    return __builtin_bit_cast(unsigned short, __float2bfloat16(v));
}
__device__ __forceinline__ float b2f(unsigned short u) {
    return __builtin_bit_cast(float, (unsigned)u << 16);
}

// -------- sanitize routing indices: accepts int32 / int64 / float32 encodings ------
__global__ void fix_o_kernel(const int* __restrict__ o_raw, int* __restrict__ e, int B) {
    __shared__ int oddzero, oor;
    if (threadIdx.x == 0) { oddzero = 1; oor = 0; }
    __syncthreads();
    int lodd = 1, loor = 0;
    for (int r = threadIdx.x; r < B; r += 1024) {
        int v = o_raw[r];
        if (r & 1) lodd &= (v == 0);
        if (v < 0 || v >= 8) loor = 1;
    }
    if (!lodd) atomicAnd(&oddzero, 0);
    if (loor) atomicOr(&oor, 1);
    __syncthreads();
    for (int r = threadIdx.x; r < B; r += 1024) {
        int v;
        if (oddzero) v = o_raw[2 * r];                                   // int64
        else if (oor) v = (int)__builtin_bit_cast(float, o_raw[r]);      // float
        else v = o_raw[r];                                               // int32
        e[r] = v & 7;
    }
}

// ---------------- elementwise f32 -> bf16 cast (n divisible by 1024) ----------------
__global__ void cast_bf16_kernel(const float* __restrict__ in,
                                 unsigned short* __restrict__ out, int n) {
    int i = (blockIdx.x * 256 + threadIdx.x) * 4;
    if (i + 3 < n) {
        float4 v = *reinterpret_cast<const float4*>(in + i);
        ushort4 o;
        o.x = f2b(v.x); o.y = f2b(v.y); o.z = f2b(v.z); o.w = f2b(v.w);
        *reinterpret_cast<ushort4*>(out + i) = o;
    }
}

// ---------------- tiled transpose-cast: in f32 [Rr][Cc] -> out bf16 [Cc][Rr] --------
__global__ void tcast_kernel(const float* __restrict__ in,
                             unsigned short* __restrict__ out,
                             int Rr, int Cc, long bsi, long bso) {
    __shared__ float t[32][33];
    const float* src = in + (size_t)blockIdx.z * bsi;
    unsigned short* dst = out + (size_t)blockIdx.z * bso;
    int r0 = blockIdx.y * 32, c0 = blockIdx.x * 32;
    int tx = threadIdx.x, ty = threadIdx.y;
#pragma unroll
    for (int j = 0; j < 4; ++j)
        t[ty + j * 8][tx] = src[(size_t)(r0 + ty + j * 8) * Cc + c0 + tx];
    __syncthreads();
#pragma unroll
    for (int j = 0; j < 4; ++j)
        dst[(size_t)(c0 + ty + j * 8) * Rr + r0 + tx] = f2b(t[tx][ty + j * 8]);
}

// ---------------- bf16 GEMM, A[M][K] row-major, Bt[N][K] row-major (= B^T) ----------
// 128x128 tile, 4 waves (64x64 each), BK=32, mfma_f32_16x16x32_bf16, reg-staged LDS.
// EPI 0: outB = bf16(acc + bias[col])
// EPI 2: outB = bf16( (col>>7)==e[row] ? acc+bias[col] : 0 )   (expert mask)
// EPI 3: outB = bf16( elu(acc + bias2[e[row]*N+col] + b2f(main_in[row*N+col])) )
template <int EPI>
__global__ __launch_bounds__(256) void gemm_kernel(
    const unsigned short* __restrict__ Ag, const unsigned short* __restrict__ Btg,
    int M, int N, int K,
    const float* __restrict__ bias, const int* __restrict__ eo,
    const float* __restrict__ bias2, const unsigned short* __restrict__ main_in,
    unsigned short* __restrict__ outB) {
    __shared__ __align__(16) unsigned short Alds[128 * 32];
    __shared__ __align__(16) unsigned short Blds[128 * 32];
    const int tid = threadIdx.x;
    const int lane = tid & 63;
    const int wid = tid >> 6;
    const int lo = lane & 15, hi = lane >> 4;
    const int m0 = blockIdx.x * 128, n0 = blockIdx.y * 128;
    const int wm = (wid & 1) * 64, wn = (wid >> 1) * 64;

    f32x4 acc[4][4] = {};

    for (int k0 = 0; k0 < K; k0 += 32) {
        bf16x8 stg[4];
#pragma unroll
        for (int t = 0; t < 4; ++t) {
            int c = t * 256 + tid;
            const unsigned short* g;
            if (c < 512) {              // A tile: row c>>2, k-chunk c&3
                g = Ag + (size_t)(m0 + (c >> 2)) * K + k0 + (c & 3) * 8;
            } else {                    // B tile (Bt rows = output cols)
                int d = c - 512;
                g = Btg + (size_t)(n0 + (d >> 2)) * K + k0 + (d & 3) * 8;
            }
            stg[t] = *reinterpret_cast<const bf16x8*>(g);
        }
        __syncthreads();  // WAR: previous iteration's LDS reads complete
#pragma unroll
        for (int t = 0; t < 4; ++t) {
            int c = t * 256 + tid;
            unsigned short* p = (c < 512) ? (Alds + (size_t)c * 8)
                                          : (Blds + (size_t)(c - 512) * 8);
            *reinterpret_cast<bf16x8*>(p) = stg[t];
        }
        __syncthreads();  // RAW: LDS writes visible

        bf16x8 af[4], bfr[4];
#pragma unroll
        for (int mi = 0; mi < 4; ++mi)
            af[mi] = *reinterpret_cast<const bf16x8*>(
                &Alds[(wm + mi * 16 + lo) * 32 + hi * 8]);
#pragma unroll
        for (int ni = 0; ni < 4; ++ni)
            bfr[ni] = *reinterpret_cast<const bf16x8*>(
                &Blds[(wn + ni * 16 + lo) * 32 + hi * 8]);
#pragma unroll
        for (int mi = 0; mi < 4; ++mi)
#pragma unroll
            for (int ni = 0; ni < 4; ++ni)
                acc[mi][ni] = __builtin_amdgcn_mfma_f32_16x16x32_bf16(
                    af[mi], bfr[ni], acc[mi][ni], 0, 0, 0);
    }

    // epilogue: acc[mi][ni][r] -> C[m0+wm+mi*16+hi*4+r][n0+wn+ni*16+lo]
#pragma unroll
    for (int mi = 0; mi < 4; ++mi) {
        const int mrow = m0 + wm + mi * 16 + hi * 4;
#pragma unroll
        for (int ni = 0; ni < 4; ++ni) {
            const int col = n0 + wn + ni * 16 + lo;
            if constexpr (EPI == 0) {
                float bv = bias[col];
#pragma unroll
                for (int r = 0; r < 4; ++r)
                    outB[(size_t)(mrow + r) * N + col] = f2b(acc[mi][ni][r] + bv);
            } else if constexpr (EPI == 2) {
                float bv = bias[col];
                int ce = col >> 7;
#pragma unroll
                for (int r = 0; r < 4; ++r) {
                    float v = ((eo[mrow + r] & 7) == ce) ? (acc[mi][ni][r] + bv)
                                                         : 0.0f;
                    outB[(size_t)(mrow + r) * N + col] = f2b(v);
                }
            } else {
#pragma unroll
                for (int r = 0; r < 4; ++r) {
                    int row = mrow + r;
                    float v = acc[mi][ni][r] +
                              bias2[(size_t)(eo[row] & 7) * N + col] +
                              b2f(main_in[(size_t)row * N + col]);
                    v = v > 0.0f ? v : expm1f(v);
                    outB[(size_t)row * N + col] = f2b(v);
                }
            }
        }
    }
}

// ---------------- final GEMM: [BBB x HH] @ [HH x 64] -> f32 d_out + bias ----------
// 128x64 tile (grid BBB/128 blocks), 4 waves each 32 rows x 64 cols, BK=32.
__global__ __launch_bounds__(256) void gemm_out_kernel(
    const unsigned short* __restrict__ Ag, const unsigned short* __restrict__ Btg,
    const float* __restrict__ bias, float* __restrict__ outF) {
    __shared__ __align__(16) unsigned short Alds[128 * 32];
    __shared__ __align__(16) unsigned short Blds[64 * 32];
    const int tid = threadIdx.x;
    const int lane = tid & 63;
    const int wid = tid >> 6;
    const int lo = lane & 15, hi = lane >> 4;
    const int m0 = blockIdx.x * 128;
    const int wm = wid * 32;

    f32x4 acc[2][4] = {};

    for (int k0 = 0; k0 < HH; k0 += 32) {
        bf16x8 stg[3];
#pragma unroll
        for (int t = 0; t < 2; ++t) {  // A tile: 512 chunks
            int c = t * 256 + tid;
            stg[t] = *reinterpret_cast<const bf16x8*>(
                Ag + (size_t)(m0 + (c >> 2)) * HH + k0 + (c & 3) * 8);
        }
        // B tile: 64 rows x 32k = 256 chunks
        stg[2] = *reinterpret_cast<const bf16x8*>(
            Btg + (size_t)(tid >> 2) * HH + k0 + (tid & 3) * 8);
        __syncthreads();
#pragma unroll
        for (int t = 0; t < 2; ++t) {
            int c = t * 256 + tid;
            *reinterpret_cast<bf16x8*>(Alds + (size_t)c * 8) = stg[t];
        }
        *reinterpret_cast<bf16x8*>(Blds + (size_t)tid * 8) = stg[2];
        __syncthreads();

        bf16x8 af[2], bfr[4];
#pragma unroll
        for (int mi = 0; mi < 2; ++mi)
            af[mi] = *reinterpret_cast<const bf16x8*>(
                &Alds[(wm + mi * 16 + lo) * 32 + hi * 8]);
#pragma unroll
        for (int ni = 0; ni < 4; ++ni)
            bfr[ni] = *reinterpret_cast<const bf16x8*>(
                &Blds[(ni * 16 + lo) * 32 + hi * 8]);
#pragma unroll
        for (int mi = 0; mi < 2; ++mi)
#pragma unroll
            for (int ni = 0; ni < 4; ++ni)
                acc[mi][ni] = __builtin_amdgcn_mfma_f32_16x16x32_bf16(
                    af[mi], bfr[ni], acc[mi][ni], 0, 0, 0);
    }

#pragma unroll
    for (int mi = 0; mi < 2; ++mi) {
        const int mrow = m0 + wm + mi * 16 + hi * 4;
#pragma unroll
        for (int ni = 0; ni < 4; ++ni) {
            const int col = ni * 16 + lo;
            float bv = bias[col];
#pragma unroll
            for (int r = 0; r < 4; ++r)
                outF[(size_t)(mrow + r) * AOUT + col] = acc[mi][ni][r] + bv;
        }
    }
}

extern "C" void kernel_launch(void* const* d_in, const int* in_sizes, int n_in,
                              void* d_out, int out_size, void* d_ws, size_t ws_size,
                              hipStream_t stream) {
    const float* s      = (const float*)d_in[0];
    const int*   o_raw  = (const int*)d_in[1];
    const float* W_in   = (const float*)d_in[2];
    const float* b_in   = (const float*)d_in[3];
    const float* W_main = (const float*)d_in[4];
    const float* b_main = (const float*)d_in[5];
    const float* W_g1   = (const float*)d_in[6];
    const float* b_g1   = (const float*)d_in[7];
    const float* W_g2   = (const float*)d_in[8];
    const float* b_g2   = (const float*)d_in[9];
    const float* W_out  = (const float*)d_in[10];   // [HH][64] = 131072 elems
    const float* b_out  = (const float*)d_in[11];   // [64]
    (void)in_sizes; (void)n_in; (void)out_size;

    // ---- workspace: e 64KB | X 16MB | Wt 8MB | sbuf 8MB | mainb 8MB = 40.06MB ----
    // d_out = f32 [BBB][64] = 1MB, written exactly once by gemm_out_kernel.
    char* ws = (char*)d_ws;
    size_t off = 0;
    auto alloc = [&](size_t bytes) {
        void* p = ws + off;
        off += (bytes + 255) & ~(size_t)255;
        return p;
    };
    int*            e     = (int*)alloc(65536);
    unsigned short* X     = (unsigned short*)alloc((size_t)BBB * HH * 2);      // 16MB
    unsigned short* Wt    = (unsigned short*)alloc((size_t)HH * HH * 2);       //  8MB
    unsigned short* sbuf  = (unsigned short*)alloc((size_t)BBB * GG * RR * 2); //  8MB
    unsigned short* mainb = (unsigned short*)alloc((size_t)BBB * HH * 2);      //  8MB
    if (ws_size < off) return;  // clean absmax failure instead of OOB fault

    dim3 tb(32, 8);

    fix_o_kernel<<<1, 1024, 0, stream>>>(o_raw, e, BBB);

    // X = bf16(s @ W_in + b_in)
    cast_bf16_kernel<<<BBB * SS / 1024, 256, 0, stream>>>(s, sbuf, BBB * SS);
    tcast_kernel<<<dim3(HH / 32, SS / 32, 1), tb, 0, stream>>>(W_in, Wt, SS, HH, 0, 0);
    gemm_kernel<0><<<dim3(BBB / 128, HH / 128), 256, 0, stream>>>(
        sbuf, Wt, BBB, HH, SS, b_in, nullptr, nullptr, nullptr, X);

    for (int i = 0; i < LL; ++i) {
        // mainb = bf16(X @ W_main[i] + b_main[i])
        tcast_kernel<<<dim3(HH / 32, HH / 32, 1), tb, 0, stream>>>(
            W_main + (size_t)i * HH * HH, Wt, HH, HH, 0, 0);
        gemm_kernel<0><<<dim3(BBB / 128, HH / 128), 256, 0, stream>>>(
            X, Wt, BBB, HH, HH, b_main + i * HH, nullptr, nullptr, nullptr, mainb);
        // h1m = mask(X @ W_g1[i] + b_g1[i]) -> bf16 [B][G*R] in sbuf
        tcast_kernel<<<dim3(RR / 32, HH / 32, GG), tb, 0, stream>>>(
            W_g1 + (size_t)i * GG * HH * RR, Wt, HH, RR, (long)HH * RR,
            (long)RR * HH);
        gemm_kernel<2><<<dim3(BBB / 128, GG * RR / 128), 256, 0, stream>>>(
            X, Wt, BBB, GG * RR, HH, b_g1 + i * GG * RR, e, nullptr, nullptr, sbuf);
        // X = bf16(elu(mainb + h1m @ W_g2[i] + b_g2[i][o]))
        tcast_kernel<<<dim3(HH / 32, GG * RR / 32, 1), tb, 0, stream>>>(
            W_g2 + (size_t)i * GG * RR * HH, Wt, GG * RR, HH, 0, 0);
        gemm_kernel<3><<<dim3(BBB / 128, HH / 128), 256, 0, stream>>>(
            sbuf, Wt, BBB, HH, GG * RR, nullptr, e, b_g2 + (size_t)i * GG * HH,
            mainb, X);
    }

    // logits = X @ W_out + b_out -> f32 d_out  (W_out^T = [64][HH] bf16, 256KB)
    tcast_kernel<<<dim3(AOUT / 32, HH / 32, 1), tb, 0, stream>>>(W_out, Wt, HH,
                                                                AOUT, 0, 0);
    gemm_out_kernel<<<BBB / 128, 256, 0, stream>>>(X, Wt, b_out, (float*)d_out);
}

// Round 9
// 817.413 us; speedup vs baseline: 1.0787x; 1.0787x over previous
//
#include <hip/hip_runtime.h>
#include <hip/hip_bf16.h>

#define LL 4
#define GG 8
#define HH 2048
#define RR 128
#define SS 512
#define AOUT 64
#define BBB 4096

typedef __bf16 bf16x8 __attribute__((ext_vector_type(8)));
typedef float f32x4 __attribute__((ext_vector_type(4)));

__device__ __forceinline__ unsigned short f2b(float v) {
    return __builtin_bit_cast(unsigned short, __float2bfloat16(v));
}
__device__ __forceinline__ float b2f(unsigned short u) {
    return __builtin_bit_cast(float, (unsigned)u << 16);
}

// -------- sanitize routing indices: accepts int32 / int64 / float32 encodings ------
__global__ void fix_o_kernel(const int* __restrict__ o_raw, int* __restrict__ e, int B) {
    __shared__ int oddzero, oor;
    if (threadIdx.x == 0) { oddzero = 1; oor = 0; }
    __syncthreads();
    int lodd = 1, loor = 0;
    for (int r = threadIdx.x; r < B; r += 1024) {
        int v = o_raw[r];
        if (r & 1) lodd &= (v == 0);
        if (v < 0 || v >= 8) loor = 1;
    }
    if (!lodd) atomicAnd(&oddzero, 0);
    if (loor) atomicOr(&oor, 1);
    __syncthreads();
    for (int r = threadIdx.x; r < B; r += 1024) {
        int v;
        if (oddzero) v = o_raw[2 * r];                                   // int64
        else if (oor) v = (int)__builtin_bit_cast(float, o_raw[r]);      // float
        else v = o_raw[r];                                               // int32
        e[r] = v & 7;
    }
}

// ---------------- elementwise f32 -> bf16 cast (n divisible by 1024) ----------------
__global__ void cast_bf16_kernel(const float* __restrict__ in,
                                 unsigned short* __restrict__ out, int n) {
    int i = (blockIdx.x * 256 + threadIdx.x) * 4;
    if (i + 3 < n) {
        float4 v = *reinterpret_cast<const float4*>(in + i);
        ushort4 o;
        o.x = f2b(v.x); o.y = f2b(v.y); o.z = f2b(v.z); o.w = f2b(v.w);
        *reinterpret_cast<ushort4*>(out + i) = o;
    }
}

// ---------------- tiled transpose-cast: in f32 [Rr][Cc] -> out bf16 [Cc][Rr] --------
__global__ void tcast_kernel(const float* __restrict__ in,
                             unsigned short* __restrict__ out,
                             int Rr, int Cc, long bsi, long bso) {
    __shared__ float t[32][33];
    const float* src = in + (size_t)blockIdx.z * bsi;
    unsigned short* dst = out + (size_t)blockIdx.z * bso;
    int r0 = blockIdx.y * 32, c0 = blockIdx.x * 32;
    int tx = threadIdx.x, ty = threadIdx.y;
#pragma unroll
    for (int j = 0; j < 4; ++j)
        t[ty + j * 8][tx] = src[(size_t)(r0 + ty + j * 8) * Cc + c0 + tx];
    __syncthreads();
#pragma unroll
    for (int j = 0; j < 4; ++j)
        dst[(size_t)(c0 + ty + j * 8) * Rr + r0 + tx] = f2b(t[tx][ty + j * 8]);
}

// ---------------- bf16 GEMM, A[M][K] row-major, Bt[N][K] row-major (= B^T) ----------
// 128x128 tile, 4 waves (64x64 each), BK=32, mfma_f32_16x16x32_bf16.
// global_load_lds width-16 staging (m97 structure; A/B vs round-8 reg-staging).
// EPI 0: outB = bf16(acc + bias[col])
// EPI 2: outB = bf16( (col>>7)==e[row] ? acc+bias[col] : 0 )   (expert mask)
// EPI 3: outB = bf16( elu(acc + bias2[e[row]*N+col] + b2f(main_in[row*N+col])) )
template <int EPI>
__global__ __launch_bounds__(256) void gemm_kernel(
    const unsigned short* __restrict__ Ag, const unsigned short* __restrict__ Btg,
    int M, int N, int K,
    const float* __restrict__ bias, const int* __restrict__ eo,
    const float* __restrict__ bias2, const unsigned short* __restrict__ main_in,
    unsigned short* __restrict__ outB) {
    __shared__ __align__(16) unsigned short Alds[128 * 32];
    __shared__ __align__(16) unsigned short Blds[128 * 32];
    const int tid = threadIdx.x;
    const int lane = tid & 63;
    const int wid = tid >> 6;
    const int lo = lane & 15, hi = lane >> 4;
    const int m0 = blockIdx.x * 128, n0 = blockIdx.y * 128;
    const int wm = (wid & 1) * 64, wn = (wid >> 1) * 64;

    f32x4 acc[4][4] = {};

    for (int k0 = 0; k0 < K; k0 += 32) {
#pragma unroll
        for (int t = 0; t < 4; ++t) {
            int c = t * 256 + tid;
            if (c < 512) {  // A tile: 128 rows x 32 k; chunk c -> row c>>2, k-part c&3
                const unsigned short* g =
                    Ag + (size_t)(m0 + (c >> 2)) * K + k0 + (c & 3) * 8;
                __builtin_amdgcn_global_load_lds(
                    (const __attribute__((address_space(1))) void*)g,
                    (__attribute__((address_space(3))) void*)(Alds + (size_t)c * 8),
                    16, 0, 0);
            } else {        // B tile (Bt rows = output cols)
                int d = c - 512;
                const unsigned short* g =
                    Btg + (size_t)(n0 + (d >> 2)) * K + k0 + (d & 3) * 8;
                __builtin_amdgcn_global_load_lds(
                    (const __attribute__((address_space(1))) void*)g,
                    (__attribute__((address_space(3))) void*)(Blds + (size_t)d * 8),
                    16, 0, 0);
            }
        }
        asm volatile("s_waitcnt vmcnt(0)" ::: "memory");
        __syncthreads();

        bf16x8 af[4], bfr[4];
#pragma unroll
        for (int mi = 0; mi < 4; ++mi)
            af[mi] = *reinterpret_cast<const bf16x8*>(
                &Alds[(wm + mi * 16 + lo) * 32 + hi * 8]);
#pragma unroll
        for (int ni = 0; ni < 4; ++ni)
            bfr[ni] = *reinterpret_cast<const bf16x8*>(
                &Blds[(wn + ni * 16 + lo) * 32 + hi * 8]);
#pragma unroll
        for (int mi = 0; mi < 4; ++mi)
#pragma unroll
            for (int ni = 0; ni < 4; ++ni)
                acc[mi][ni] = __builtin_amdgcn_mfma_f32_16x16x32_bf16(
                    af[mi], bfr[ni], acc[mi][ni], 0, 0, 0);
        __syncthreads();
    }

    // epilogue: acc[mi][ni][r] -> C[m0+wm+mi*16+hi*4+r][n0+wn+ni*16+lo]
#pragma unroll
    for (int mi = 0; mi < 4; ++mi) {
        const int mrow = m0 + wm + mi * 16 + hi * 4;
#pragma unroll
        for (int ni = 0; ni < 4; ++ni) {
            const int col = n0 + wn + ni * 16 + lo;
            if constexpr (EPI == 0) {
                float bv = bias[col];
#pragma unroll
                for (int r = 0; r < 4; ++r)
                    outB[(size_t)(mrow + r) * N + col] = f2b(acc[mi][ni][r] + bv);
            } else if constexpr (EPI == 2) {
                float bv = bias[col];
                int ce = col >> 7;
#pragma unroll
                for (int r = 0; r < 4; ++r) {
                    float v = ((eo[mrow + r] & 7) == ce) ? (acc[mi][ni][r] + bv)
                                                         : 0.0f;
                    outB[(size_t)(mrow + r) * N + col] = f2b(v);
                }
            } else {
#pragma unroll
                for (int r = 0; r < 4; ++r) {
                    int row = mrow + r;
                    float v = acc[mi][ni][r] +
                              bias2[(size_t)(eo[row] & 7) * N + col] +
                              b2f(main_in[(size_t)row * N + col]);
                    v = v > 0.0f ? v : expm1f(v);
                    outB[(size_t)row * N + col] = f2b(v);
                }
            }
        }
    }
}

// ---------------- final GEMM: [BBB x HH] @ [HH x 64] -> f32 d_out + bias ----------
// 128x64 tile (grid BBB/128 blocks), 4 waves each 32 rows x 64 cols, BK=32.
__global__ __launch_bounds__(256) void gemm_out_kernel(
    const unsigned short* __restrict__ Ag, const unsigned short* __restrict__ Btg,
    const float* __restrict__ bias, float* __restrict__ outF) {
    __shared__ __align__(16) unsigned short Alds[128 * 32];
    __shared__ __align__(16) unsigned short Blds[64 * 32];
    const int tid = threadIdx.x;
    const int lane = tid & 63;
    const int wid = tid >> 6;
    const int lo = lane & 15, hi = lane >> 4;
    const int m0 = blockIdx.x * 128;
    const int wm = wid * 32;

    f32x4 acc[2][4] = {};

    for (int k0 = 0; k0 < HH; k0 += 32) {
#pragma unroll
        for (int t = 0; t < 2; ++t) {  // A tile: 512 chunks of 16B
            int c = t * 256 + tid;
            const unsigned short* g =
                Ag + (size_t)(m0 + (c >> 2)) * HH + k0 + (c & 3) * 8;
            __builtin_amdgcn_global_load_lds(
                (const __attribute__((address_space(1))) void*)g,
                (__attribute__((address_space(3))) void*)(Alds + (size_t)c * 8),
                16, 0, 0);
        }
        {   // B tile: 64 rows x 32 k = 256 chunks
            const unsigned short* g =
                Btg + (size_t)(tid >> 2) * HH + k0 + (tid & 3) * 8;
            __builtin_amdgcn_global_load_lds(
                (const __attribute__((address_space(1))) void*)g,
                (__attribute__((address_space(3))) void*)(Blds + (size_t)tid * 8),
                16, 0, 0);
        }
        asm volatile("s_waitcnt vmcnt(0)" ::: "memory");
        __syncthreads();

        bf16x8 af[2], bfr[4];
#pragma unroll
        for (int mi = 0; mi < 2; ++mi)
            af[mi] = *reinterpret_cast<const bf16x8*>(
                &Alds[(wm + mi * 16 + lo) * 32 + hi * 8]);
#pragma unroll
        for (int ni = 0; ni < 4; ++ni)
            bfr[ni] = *reinterpret_cast<const bf16x8*>(
                &Blds[(ni * 16 + lo) * 32 + hi * 8]);
#pragma unroll
        for (int mi = 0; mi < 2; ++mi)
#pragma unroll
            for (int ni = 0; ni < 4; ++ni)
                acc[mi][ni] = __builtin_amdgcn_mfma_f32_16x16x32_bf16(
                    af[mi], bfr[ni], acc[mi][ni], 0, 0, 0);
        __syncthreads();
    }

#pragma unroll
    for (int mi = 0; mi < 2; ++mi) {
        const int mrow = m0 + wm + mi * 16 + hi * 4;
#pragma unroll
        for (int ni = 0; ni < 4; ++ni) {
            const int col = ni * 16 + lo;
            float bv = bias[col];
#pragma unroll
            for (int r = 0; r < 4; ++r)
                outF[(size_t)(mrow + r) * AOUT + col] = acc[mi][ni][r] + bv;
        }
    }
}

extern "C" void kernel_launch(void* const* d_in, const int* in_sizes, int n_in,
                              void* d_out, int out_size, void* d_ws, size_t ws_size,
                              hipStream_t stream) {
    const float* s      = (const float*)d_in[0];
    const int*   o_raw  = (const int*)d_in[1];
    const float* W_in   = (const float*)d_in[2];
    const float* b_in   = (const float*)d_in[3];
    const float* W_main = (const float*)d_in[4];
    const float* b_main = (const float*)d_in[5];
    const float* W_g1   = (const float*)d_in[6];
    const float* b_g1   = (const float*)d_in[7];
    const float* W_g2   = (const float*)d_in[8];
    const float* b_g2   = (const float*)d_in[9];
    const float* W_out  = (const float*)d_in[10];   // [HH][64]
    const float* b_out  = (const float*)d_in[11];   // [64]
    (void)in_sizes; (void)n_in; (void)out_size;

    // ---- workspace: e 64KB | X 16MB | Wt 8MB | sbuf 8MB | mainb 8MB = 40.06MB ----
    char* ws = (char*)d_ws;
    size_t off = 0;
    auto alloc = [&](size_t bytes) {
        void* p = ws + off;
        off += (bytes + 255) & ~(size_t)255;
        return p;
    };
    int*            e     = (int*)alloc(65536);
    unsigned short* X     = (unsigned short*)alloc((size_t)BBB * HH * 2);      // 16MB
    unsigned short* Wt    = (unsigned short*)alloc((size_t)HH * HH * 2);       //  8MB
    unsigned short* sbuf  = (unsigned short*)alloc((size_t)BBB * GG * RR * 2); //  8MB
    unsigned short* mainb = (unsigned short*)alloc((size_t)BBB * HH * 2);      //  8MB
    if (ws_size < off) return;  // clean absmax failure instead of OOB fault

    dim3 tb(32, 8);

    fix_o_kernel<<<1, 1024, 0, stream>>>(o_raw, e, BBB);

    // X = bf16(s @ W_in + b_in)
    cast_bf16_kernel<<<BBB * SS / 1024, 256, 0, stream>>>(s, sbuf, BBB * SS);
    tcast_kernel<<<dim3(HH / 32, SS / 32, 1), tb, 0, stream>>>(W_in, Wt, SS, HH, 0, 0);
    gemm_kernel<0><<<dim3(BBB / 128, HH / 128), 256, 0, stream>>>(
        sbuf, Wt, BBB, HH, SS, b_in, nullptr, nullptr, nullptr, X);

    for (int i = 0; i < LL; ++i) {
        // mainb = bf16(X @ W_main[i] + b_main[i])
        tcast_kernel<<<dim3(HH / 32, HH / 32, 1), tb, 0, stream>>>(
            W_main + (size_t)i * HH * HH, Wt, HH, HH, 0, 0);
        gemm_kernel<0><<<dim3(BBB / 128, HH / 128), 256, 0, stream>>>(
            X, Wt, BBB, HH, HH, b_main + i * HH, nullptr, nullptr, nullptr, mainb);
        // h1m = mask(X @ W_g1[i] + b_g1[i]) -> bf16 [B][G*R] in sbuf
        tcast_kernel<<<dim3(RR / 32, HH / 32, GG), tb, 0, stream>>>(
            W_g1 + (size_t)i * GG * HH * RR, Wt, HH, RR, (long)HH * RR,
            (long)RR * HH);
        gemm_kernel<2><<<dim3(BBB / 128, GG * RR / 128), 256, 0, stream>>>(
            X, Wt, BBB, GG * RR, HH, b_g1 + i * GG * RR, e, nullptr, nullptr, sbuf);
        // X = bf16(elu(mainb + h1m @ W_g2[i] + b_g2[i][o]))
        tcast_kernel<<<dim3(HH / 32, GG * RR / 32, 1), tb, 0, stream>>>(
            W_g2 + (size_t)i * GG * RR * HH, Wt, GG * RR, HH, 0, 0);
        gemm_kernel<3><<<dim3(BBB / 128, HH / 128), 256, 0, stream>>>(
            sbuf, Wt, BBB, HH, GG * RR, nullptr, e, b_g2 + (size_t)i * GG * HH,
            mainb, X);
    }

    // logits = X @ W_out + b_out -> f32 d_out  (W_out^T = [64][HH] bf16, 256KB)
    tcast_kernel<<<dim3(AOUT / 32, HH / 32, 1), tb, 0, stream>>>(W_out, Wt, HH,
                                                                AOUT, 0, 0);
    gemm_out_kernel<<<BBB / 128, 256, 0, stream>>>(X, Wt, b_out, (float*)d_out);
}

// Round 11
// 668.742 us; speedup vs baseline: 1.3185x; 1.2223x over previous
//
#include <hip/hip_runtime.h>
#include <hip/hip_bf16.h>

#define LL 4
#define GG 8
#define HH 2048
#define RR 128
#define SS 512
#define AOUT 64
#define BBB 4096

typedef __bf16 bf16x8 __attribute__((ext_vector_type(8)));
typedef float f32x4 __attribute__((ext_vector_type(4)));

__device__ __forceinline__ unsigned short f2b(float v) {
    return __builtin_bit_cast(unsigned short, __float2bfloat16(v));
}
__device__ __forceinline__ float b2f(unsigned short u) {
    return __builtin_bit_cast(float, (unsigned)u << 16);
}

// -------- sanitize routing indices: accepts int32 / int64 / float32 encodings ------
__global__ void fix_o_kernel(const int* __restrict__ o_raw, int* __restrict__ e, int B) {
    __shared__ int oddzero, oor;
    if (threadIdx.x == 0) { oddzero = 1; oor = 0; }
    __syncthreads();
    int lodd = 1, loor = 0;
    for (int r = threadIdx.x; r < B; r += 1024) {
        int v = o_raw[r];
        if (r & 1) lodd &= (v == 0);
        if (v < 0 || v >= 8) loor = 1;
    }
    if (!lodd) atomicAnd(&oddzero, 0);
    if (loor) atomicOr(&oor, 1);
    __syncthreads();
    for (int r = threadIdx.x; r < B; r += 1024) {
        int v;
        if (oddzero) v = o_raw[2 * r];
        else if (oor) v = (int)__builtin_bit_cast(float, o_raw[r]);
        else v = o_raw[r];
        e[r] = v & 7;
    }
}

// ---------------- elementwise f32 -> bf16 cast ----------------
__global__ void cast_bf16_kernel(const float* __restrict__ in,
                                 unsigned short* __restrict__ out, int n) {
    int i = (blockIdx.x * 256 + threadIdx.x) * 4;
    if (i + 3 < n) {
        float4 v = *reinterpret_cast<const float4*>(in + i);
        ushort4 o;
        o.x = f2b(v.x); o.y = f2b(v.y); o.z = f2b(v.z); o.w = f2b(v.w);
        *reinterpret_cast<ushort4*>(out + i) = o;
    }
}

// ---------------- tiled transpose-cast: f32 [Rr][Cc] -> bf16 [Cc][Rr] --------------
__global__ void tcast_kernel(const float* __restrict__ in,
                             unsigned short* __restrict__ out,
                             int Rr, int Cc, long bsi, long bso) {
    __shared__ float t[32][33];
    const float* src = in + (size_t)blockIdx.z * bsi;
    unsigned short* dst = out + (size_t)blockIdx.z * bso;
    int r0 = blockIdx.y * 32, c0 = blockIdx.x * 32;
    int tx = threadIdx.x, ty = threadIdx.y;
#pragma unroll
    for (int j = 0; j < 4; ++j)
        t[ty + j * 8][tx] = src[(size_t)(r0 + ty + j * 8) * Cc + c0 + tx];
    __syncthreads();
#pragma unroll
    for (int j = 0; j < 4; ++j)
        dst[(size_t)(c0 + ty + j * 8) * Rr + r0 + tx] = f2b(t[tx][ty + j * 8]);
}

// ---------------- bf16 GEMM, A[M][K] rm, Bt[N][K] rm, 128x128 tile, dbuf prefetch --
// T3-minimal 2-phase: STAGE(next) -> ds_read(cur)+MFMA -> vmcnt(0)+barrier.
// EPI 0: outB[row*N+col]  = bf16(acc + bias[col])
// EPI 3: outB = bf16( elu(acc + bias2[e*N+col] + b2f(main_in)) )
// EPI 4 (fused main|g1, B has 3072 rows): n0<2048 -> mainb (stride HH, bias);
//        n0>=2048 -> hc=col-2048, masked (e==hc>>7), biasg[hc] -> outB2 stride G*R.
template <int EPI>
__global__ __launch_bounds__(256) void gemm_kernel(
    const unsigned short* __restrict__ Ag, const unsigned short* __restrict__ Btg,
    int M, int N, int K,
    const float* __restrict__ bias, const float* __restrict__ biasg,
    const int* __restrict__ eo, const float* __restrict__ bias2,
    const unsigned short* __restrict__ main_in,
    unsigned short* __restrict__ outB, unsigned short* __restrict__ outB2) {
    __shared__ __align__(16) unsigned short Alds[2][128 * 32];
    __shared__ __align__(16) unsigned short Blds[2][128 * 32];
    const int tid = threadIdx.x;
    const int lane = tid & 63;
    const int wid = tid >> 6;
    const int lo = lane & 15, hi = lane >> 4;
    const int m0 = blockIdx.x * 128, n0 = blockIdx.y * 128;
    const int wm = (wid & 1) * 64, wn = (wid >> 1) * 64;
    const int NT = K >> 5;

    f32x4 acc[4][4] = {};

    auto STAGE = [&](int b, int kt) {
        const int k0 = kt << 5;
#pragma unroll
        for (int t = 0; t < 4; ++t) {
            int c = t * 256 + tid;
            if (c < 512) {  // A tile: row c>>2, k-chunk c&3
                const unsigned short* g =
                    Ag + (size_t)(m0 + (c >> 2)) * K + k0 + (c & 3) * 8;
                __builtin_amdgcn_global_load_lds(
                    (const __attribute__((address_space(1))) void*)g,
                    (__attribute__((address_space(3))) void*)(&Alds[b][c * 8]),
                    16, 0, 0);
            } else {
                int d = c - 512;
                const unsigned short* g =
                    Btg + (size_t)(n0 + (d >> 2)) * K + k0 + (d & 3) * 8;
                __builtin_amdgcn_global_load_lds(
                    (const __attribute__((address_space(1))) void*)g,
                    (__attribute__((address_space(3))) void*)(&Blds[b][d * 8]),
                    16, 0, 0);
            }
        }
    };

    // prologue: fill buf0, drain, sync
    STAGE(0, 0);
    asm volatile("s_waitcnt vmcnt(0)" ::: "memory");
    __syncthreads();

    int cur = 0;
    for (int kt = 0; kt < NT; ++kt) {
        if (kt + 1 < NT) STAGE(cur ^ 1, kt + 1);  // prefetch flies during MFMA

        bf16x8 af[4], bfr[4];
#pragma unroll
        for (int mi = 0; mi < 4; ++mi)
            af[mi] = *reinterpret_cast<const bf16x8*>(
                &Alds[cur][(wm + mi * 16 + lo) * 32 + hi * 8]);
#pragma unroll
        for (int ni = 0; ni < 4; ++ni)
            bfr[ni] = *reinterpret_cast<const bf16x8*>(
                &Blds[cur][(wn + ni * 16 + lo) * 32 + hi * 8]);
#pragma unroll
        for (int mi = 0; mi < 4; ++mi)
#pragma unroll
            for (int ni = 0; ni < 4; ++ni)
                acc[mi][ni] = __builtin_amdgcn_mfma_f32_16x16x32_bf16(
                    af[mi], bfr[ni], acc[mi][ni], 0, 0, 0);

        asm volatile("s_waitcnt vmcnt(0)" ::: "memory");  // next tile landed
        __syncthreads();  // all waves done reading cur + next tile visible
        cur ^= 1;
    }

    // epilogue: acc[mi][ni][r] -> C[m0+wm+mi*16+hi*4+r][n0+wn+ni*16+lo]
#pragma unroll
    for (int mi = 0; mi < 4; ++mi) {
        const int mrow = m0 + wm + mi * 16 + hi * 4;
#pragma unroll
        for (int ni = 0; ni < 4; ++ni) {
            const int col = n0 + wn + ni * 16 + lo;
            if constexpr (EPI == 0) {
                float bv = bias[col];
#pragma unroll
                for (int r = 0; r < 4; ++r)
                    outB[(size_t)(mrow + r) * N + col] = f2b(acc[mi][ni][r] + bv);
            } else if constexpr (EPI == 3) {
#pragma unroll
                for (int r = 0; r < 4; ++r) {
                    int row = mrow + r;
                    float v = acc[mi][ni][r] +
                              bias2[(size_t)(eo[row] & 7) * N + col] +
                              b2f(main_in[(size_t)row * N + col]);
                    v = v > 0.0f ? v : expm1f(v);
                    outB[(size_t)row * N + col] = f2b(v);
                }
            } else {  // EPI 4: fused main|g1 (branch is block-uniform in n0)
                if (n0 < HH) {
                    float bv = bias[col];
#pragma unroll
                    for (int r = 0; r < 4; ++r)
                        outB[(size_t)(mrow + r) * HH + col] =
                            f2b(acc[mi][ni][r] + bv);
                } else {
                    int hc = col - HH;
                    int ce = hc >> 7;
                    float bv = biasg[hc];
#pragma unroll
                    for (int r = 0; r < 4; ++r) {
                        float v = ((eo[mrow + r] & 7) == ce)
                                      ? (acc[mi][ni][r] + bv) : 0.0f;
                        outB2[(size_t)(mrow + r) * (GG * RR) + hc] = f2b(v);
                    }
                }
            }
        }
    }
}

// ---------------- final GEMM: [BBB x HH] @ Wt[64][HH] -> f32 d_out + bias ----------
// 64x64 tile, grid BBB/64, 4 waves (16 rows each), dbuf prefetch.
__global__ __launch_bounds__(256) void gemm_out_kernel(
    const unsigned short* __restrict__ Ag, const unsigned short* __restrict__ Btg,
    const float* __restrict__ bias, float* __restrict__ outF) {
    __shared__ __align__(16) unsigned short Alds[2][64 * 32];
    __shared__ __align__(16) unsigned short Blds[2][64 * 32];
    const int tid = threadIdx.x;
    const int lane = tid & 63;
    const int wid = tid >> 6;
    const int lo = lane & 15, hi = lane >> 4;
    const int m0 = blockIdx.x * 64;
    const int wm = wid * 16;
    const int NT = HH >> 5;

    f32x4 acc[4] = {};

    auto STAGE = [&](int b, int kt) {
        const int k0 = kt << 5;
        const int c = tid;  // 256 chunks cover a 64x32 tile
        const unsigned short* ga =
            Ag + (size_t)(m0 + (c >> 2)) * HH + k0 + (c & 3) * 8;
        __builtin_amdgcn_global_load_lds(
            (const __attribute__((address_space(1))) void*)ga,
            (__attribute__((address_space(3))) void*)(&Alds[b][c * 8]), 16, 0, 0);
        const unsigned short* gb =
            Btg + (size_t)(c >> 2) * HH + k0 + (c & 3) * 8;
        __builtin_amdgcn_global_load_lds(
            (const __attribute__((address_space(1))) void*)gb,
            (__attribute__((address_space(3))) void*)(&Blds[b][c * 8]), 16, 0, 0);
    };

    STAGE(0, 0);
    asm volatile("s_waitcnt vmcnt(0)" ::: "memory");
    __syncthreads();

    int cur = 0;
    for (int kt = 0; kt < NT; ++kt) {
        if (kt + 1 < NT) STAGE(cur ^ 1, kt + 1);
        bf16x8 af = *reinterpret_cast<const bf16x8*>(
            &Alds[cur][(wm + lo) * 32 + hi * 8]);
        bf16x8 bfr[4];
#pragma unroll
        for (int ni = 0; ni < 4; ++ni)
            bfr[ni] = *reinterpret_cast<const bf16x8*>(
                &Blds[cur][(ni * 16 + lo) * 32 + hi * 8]);
#pragma unroll
        for (int ni = 0; ni < 4; ++ni)
            acc[ni] = __builtin_amdgcn_mfma_f32_16x16x32_bf16(af, bfr[ni],
                                                              acc[ni], 0, 0, 0);
        asm volatile("s_waitcnt vmcnt(0)" ::: "memory");
        __syncthreads();
        cur ^= 1;
    }

#pragma unroll
    for (int ni = 0; ni < 4; ++ni) {
        const int col = ni * 16 + lo;
        float bv = bias[col];
#pragma unroll
        for (int r = 0; r < 4; ++r)
            outF[(size_t)(m0 + wm + hi * 4 + r) * AOUT + col] = acc[ni][r] + bv;
    }
}

extern "C" void kernel_launch(void* const* d_in, const int* in_sizes, int n_in,
                              void* d_out, int out_size, void* d_ws, size_t ws_size,
                              hipStream_t stream) {
    const float* s      = (const float*)d_in[0];
    const int*   o_raw  = (const int*)d_in[1];
    const float* W_in   = (const float*)d_in[2];
    const float* b_in   = (const float*)d_in[3];
    const float* W_main = (const float*)d_in[4];
    const float* b_main = (const float*)d_in[5];
    const float* W_g1   = (const float*)d_in[6];
    const float* b_g1   = (const float*)d_in[7];
    const float* W_g2   = (const float*)d_in[8];
    const float* b_g2   = (const float*)d_in[9];
    const float* W_out  = (const float*)d_in[10];   // [HH][64]
    const float* b_out  = (const float*)d_in[11];   // [64]
    (void)in_sizes; (void)n_in; (void)out_size;

    // ---- workspace: e 64KB | X 16MB | Wt 12.6MB | sbuf 8MB | mainb 8MB ≈ 44.7MB ----
    char* ws = (char*)d_ws;
    size_t off = 0;
    auto alloc = [&](size_t bytes) {
        void* p = ws + off;
        off += (bytes + 255) & ~(size_t)255;
        return p;
    };
    int*            e     = (int*)alloc(65536);
    unsigned short* X     = (unsigned short*)alloc((size_t)BBB * HH * 2);
    unsigned short* Wt    = (unsigned short*)alloc((size_t)(HH + GG * RR) * HH * 2);
    unsigned short* sbuf  = (unsigned short*)alloc((size_t)BBB * GG * RR * 2);
    unsigned short* mainb = (unsigned short*)alloc((size_t)BBB * HH * 2);
    if (ws_size < off) return;  // clean absmax failure instead of OOB fault

    dim3 tb(32, 8);

    fix_o_kernel<<<1, 1024, 0, stream>>>(o_raw, e, BBB);

    // X = bf16(s @ W_in + b_in)
    cast_bf16_kernel<<<BBB * SS / 1024, 256, 0, stream>>>(s, sbuf, BBB * SS);
    tcast_kernel<<<dim3(HH / 32, SS / 32, 1), tb, 0, stream>>>(W_in, Wt, SS, HH, 0, 0);
    gemm_kernel<0><<<dim3(BBB / 128, HH / 128), 256, 0, stream>>>(
        sbuf, Wt, BBB, HH, SS, b_in, nullptr, nullptr, nullptr, nullptr, X, nullptr);

    for (int i = 0; i < LL; ++i) {
        // Wt = [W_main[i]^T (2048 rows) | W_g1[i]^T (1024 rows)], each row K=HH
        tcast_kernel<<<dim3(HH / 32, HH / 32, 1), tb, 0, stream>>>(
            W_main + (size_t)i * HH * HH, Wt, HH, HH, 0, 0);
        tcast_kernel<<<dim3(RR / 32, HH / 32, GG), tb, 0, stream>>>(
            W_g1 + (size_t)i * GG * HH * RR, Wt + (size_t)HH * HH, HH, RR,
            (long)HH * RR, (long)RR * HH);
        // fused: mainb = bf16(X@W_main+b_main); sbuf = mask(X@W_g1+b_g1)
        gemm_kernel<4><<<dim3(BBB / 128, (HH + GG * RR) / 128), 256, 0, stream>>>(
            X, Wt, BBB, HH + GG * RR, HH, b_main + i * HH, b_g1 + i * GG * RR,
            e, nullptr, nullptr, mainb, sbuf);
        // X = bf16(elu(mainb + h1m @ W_g2[i] + b_g2[i][o]))
        tcast_kernel<<<dim3(HH / 32, GG * RR / 32, 1), tb, 0, stream>>>(
            W_g2 + (size_t)i * GG * RR * HH, Wt, GG * RR, HH, 0, 0);
        gemm_kernel<3><<<dim3(BBB / 128, HH / 128), 256, 0, stream>>>(
            sbuf, Wt, BBB, HH, GG * RR, nullptr, nullptr, e,
            b_g2 + (size_t)i * GG * HH, mainb, X, nullptr);
    }

    // logits = X @ W_out + b_out -> f32 d_out
    tcast_kernel<<<dim3(AOUT / 32, HH / 32, 1), tb, 0, stream>>>(W_out, Wt, HH,
                                                                AOUT, 0, 0);
    gemm_out_kernel<<<BBB / 64, 256, 0, stream>>>(X, Wt, b_out, (float*)d_out);
}